// Round 6
// baseline (269.417 us; speedup 1.0000x reference)
//
#include <hip/hip_runtime.h>
#include <stdint.h>

#define S_LEN 2048
#define D_DIM 128

typedef __attribute__((ext_vector_type(8)))  short bf16x8;
typedef __attribute__((ext_vector_type(4)))  short bf16x4;
typedef __attribute__((ext_vector_type(4)))  float f32x4;
typedef __attribute__((ext_vector_type(2)))  float f32x2;
typedef __attribute__((ext_vector_type(16))) float f32x16;

__device__ __forceinline__ short f2bf(float f) {
  union { float f; uint32_t u; } c; c.f = f;
  uint32_t u = c.u;
  u += 0x7fffu + ((u >> 16) & 1u);
  return (short)(u >> 16);
}
__device__ __forceinline__ uint32_t pk2bf(float a, float b) {
#if __has_builtin(__builtin_amdgcn_cvt_pk_bf16_f32)
  typedef __attribute__((ext_vector_type(2))) __bf16 bf2;
  union { bf2 v; uint32_t u; } cv;
  cv.v = __builtin_amdgcn_cvt_pk_bf16_f32(a, b);
  return cv.u;
#else
  return (uint32_t)(uint16_t)f2bf(a) | (((uint32_t)(uint16_t)f2bf(b)) << 16);
#endif
}
__device__ __forceinline__ bf16x8 mk8(uint32_t a, uint32_t b, uint32_t c, uint32_t d) {
  union { uint32_t u[4]; bf16x8 v; } x;
  x.u[0] = a; x.u[1] = b; x.u[2] = c; x.u[3] = d;
  return x.v;
}
__device__ __forceinline__ uint32_t lo16(uint32_t a, uint32_t b) {
  return (a & 0xffffu) | (b << 16);
}
__device__ __forceinline__ uint32_t hi16(uint32_t a, uint32_t b) {
  return (a >> 16) | (b & 0xffff0000u);
}
__device__ __forceinline__ void gl_lds16(const short* g, short* l) {
  __builtin_amdgcn_global_load_lds((const __attribute__((address_space(1))) void*)g,
                                   (__attribute__((address_space(3))) void*)l, 16, 0, 0);
}

// ---------------- preprocess (no LDS) ----------------
// blocks [0,512): K fp32->bf16 streaming convert.
// blocks [512,1024): V -> Vt bf16 [bh][d][key] with per-16 key bit2<->bit3
// permutation, via in-register 4x8 transpose (shift/or), direct global->global.
__global__ __launch_bounds__(256) void pre_kernel(
    const float* __restrict__ K, const float* __restrict__ V,
    short* __restrict__ Kb, short* __restrict__ Vt) {
  const int t = threadIdx.x;
  const int b = blockIdx.x;
  if (b < 512) {
    const f32x4* src = (const f32x4*)K + (size_t)b * 4096;
    uint2* dst = (uint2*)Kb + (size_t)b * 4096;
#pragma unroll
    for (int it = 0; it < 16; ++it) {
      f32x4 v = src[it * 256 + t];
      dst[it * 256 + t] = make_uint2(pk2bf(v[0], v[1]), pk2bf(v[2], v[3]));
    }
    return;
  }
  const int vb = b - 512;          // 0..511
  const int bh = vb >> 4;
  const int k0 = (vb & 15) * 128;
  const float* src = V + ((size_t)bh * S_LEN + k0) * D_DIM;
  short* dstBase = Vt + (size_t)bh * D_DIM * S_LEN + k0;
  const int dg = t & 31;           // d-group (4 d's)
#pragma unroll
  for (int half = 0; half < 2; ++half) {
    const int kg = (t >> 5) + half * 8;   // k-group (8 k's)
    uint32_t r[8][2];
#pragma unroll
    for (int rr = 0; rr < 8; ++rr) {
      f32x4 v = *(const f32x4*)(src + (size_t)(kg * 8 + rr) * D_DIM + dg * 4);
      r[rr][0] = pk2bf(v[0], v[1]);
      r[rr][1] = pk2bf(v[2], v[3]);
    }
    const int base1 = (kg >> 1) * 16 + (kg & 1) * 4;  // bit2<->3 permuted key pos
#pragma unroll
    for (int dd = 0; dd < 4; ++dd) {
      const int wsel = dd >> 1;
      uint32_t w0, w1, w2, w3;
      if ((dd & 1) == 0) {
        w0 = lo16(r[0][wsel], r[1][wsel]); w1 = lo16(r[2][wsel], r[3][wsel]);
        w2 = lo16(r[4][wsel], r[5][wsel]); w3 = lo16(r[6][wsel], r[7][wsel]);
      } else {
        w0 = hi16(r[0][wsel], r[1][wsel]); w1 = hi16(r[2][wsel], r[3][wsel]);
        w2 = hi16(r[4][wsel], r[5][wsel]); w3 = hi16(r[6][wsel], r[7][wsel]);
      }
      short* orow = dstBase + (size_t)(dg * 4 + dd) * S_LEN;
      *(uint2*)(orow + base1)     = make_uint2(w0, w1);
      *(uint2*)(orow + base1 + 8) = make_uint2(w2, w3);
    }
  }
}

// ---------------- main kernel ----------------
// WG 256 / 4 waves = (qp: q-half of 32, h: key-half). 64 q-rows/WG.
// Per 64-key chunk: S^T = K*Q^T (32x32x16, wave owns keys [h*32,+32), split-k
// 2 chains), exp2, in-register pack to A-frags, PV over ALL 128 d into oj[4]
// (h-partial). Per 256-key block: oa += oj * linv. Epilogue: cross-h reduce
// via LDS. 1 barrier/chunk + 1/block. K/V double-buffered global_load_lds.
__global__ __launch_bounds__(256, 2) void attn_main(
    const short* __restrict__ Kb, const short* __restrict__ Vt,
    const float* __restrict__ Q, float* __restrict__ O) {
  __shared__ __align__(16) short ring[2][16384];  // per slot: K 16KB | V 16KB
  __shared__ float sRed[128];                     // [64 q][2 h]
  __shared__ float sLinv[64];
  // total LDS = 65536 + 512 + 256 = 66304 B -> 2 blocks/CU

  const int t = threadIdx.x;
  const int w = t >> 6;
  const int lane = t & 63;
  const int l31 = lane & 31;
  const int hi = lane >> 5;
  const int h = w & 1;
  const int qp = w >> 1;

  // XCD swizzle: all 64 q-tiles of a bh land on one XCD (K/V L2-resident)
  const int b = blockIdx.x;
  const int bh = (b & 7) * 4 + ((b >> 3) & 3);
  const int q0 = (b >> 5) * 64;

  const short* Kh = Kb + (size_t)bh * S_LEN * D_DIM;
  const short* Vh = Vt + (size_t)bh * D_DIM * S_LEN;

  const int kKey = t >> 4;
  const int kG   = (t & 15) ^ (kKey & 15);
  const int vD   = t >> 3;
  const int vG   = (t & 7) ^ (vD & 7);

  auto stageK = [&](int key0, int slot) {
    const short* src = Kh + (size_t)(key0 + kKey) * D_DIM + kG * 8;
    short* dst = &ring[slot][t * 8];
#pragma unroll
    for (int r = 0; r < 4; ++r) gl_lds16(src + r * 16 * D_DIM, dst + r * 2048);
  };
  auto stageV = [&](int key0, int slot) {
    const short* src = Vh + (size_t)vD * S_LEN + key0 + vG * 8;
    short* dst = &ring[slot][8192 + t * 8];
#pragma unroll
    for (int r = 0; r < 4; ++r) gl_lds16(src + (size_t)r * 32 * S_LEN, dst + r * 2048);
  };

  // Q fragments: load fp32, scale, pack (register-resident)
  bf16x8 qf[8];
  {
    const float QSCALE = 0.12751743f;  // 128^-0.5 * log2(e)
    const float* Qg = Q + ((size_t)bh * S_LEN + q0 + qp * 32 + l31) * D_DIM;
#pragma unroll
    for (int ks = 0; ks < 8; ++ks) {
      f32x4 a = *(const f32x4*)(Qg + ks * 16 + hi * 8);
      f32x4 c = *(const f32x4*)(Qg + ks * 16 + hi * 8 + 4);
      qf[ks] = mk8(pk2bf(a[0] * QSCALE, a[1] * QSCALE), pk2bf(a[2] * QSCALE, a[3] * QSCALE),
                   pk2bf(c[0] * QSCALE, c[1] * QSCALE), pk2bf(c[2] * QSCALE, c[3] * QSCALE));
    }
  }

  int aK[8];
#pragma unroll
  for (int ks = 0; ks < 8; ++ks)
    aK[ks] = (h * 32 + l31) * 128 + (((2 * ks + hi) ^ (l31 & 15)) << 3);
  int aV2[2];
#pragma unroll
  for (int t2 = 0; t2 < 2; ++t2)
    aV2[t2] = l31 * 64 + ((((h * 2 + t2) * 2 + hi) ^ (l31 & 7)) << 3);

  f32x16 oa[4], oj[4];
#pragma unroll
  for (int d = 0; d < 4; ++d)
#pragma unroll
    for (int r = 0; r < 16; ++r) { oa[d][r] = 0.f; oj[d][r] = 0.f; }

  float ssum = 0.f;

  stageK(0, 0); stageV(0, 0);

  for (int j = 0; j < 8; ++j) {
#pragma unroll
    for (int c = 0; c < 4; ++c) {
      const int G = j * 4 + c;
      const int slot = G & 1;
      __syncthreads();  // chunk G staged; ring[slot^1] free
      if (G + 1 < 32) { stageK((G + 1) * 64, slot ^ 1); stageV((G + 1) * 64, slot ^ 1); }

      if (c == 0 && j > 0) {
        f32x4 lv[4];
#pragma unroll
        for (int g = 0; g < 4; ++g) lv[g] = *(const f32x4*)&sLinv[qp * 32 + g * 8 + hi * 4];
#pragma unroll
        for (int d = 0; d < 4; ++d)
#pragma unroll
          for (int r = 0; r < 16; ++r) {
            oa[d][r] += oj[d][r] * lv[r >> 2][r & 3];
            oj[d][r] = 0.f;
          }
      }

      // ---- QK^T: one 32x32 tile, split-k (2 chains of 4) ----
      const short* pK = &ring[slot][0];
      f32x16 sc, sc2;
#pragma unroll
      for (int r = 0; r < 16; ++r) { sc[r] = 0.f; sc2[r] = 0.f; }
#pragma unroll
      for (int ks = 0; ks < 4; ++ks) {
        bf16x8 a = *(const bf16x8*)(pK + aK[ks]);
        sc = __builtin_amdgcn_mfma_f32_32x32x16_bf16(a, qf[ks], sc, 0, 0, 0);
      }
#pragma unroll
      for (int ks = 4; ks < 8; ++ks) {
        bf16x8 a = *(const bf16x8*)(pK + aK[ks]);
        sc2 = __builtin_amdgcn_mfma_f32_32x32x16_bf16(a, qf[ks], sc2, 0, 0, 0);
      }
#pragma unroll
      for (int r = 0; r < 16; ++r) sc[r] = exp2f(sc[r] + sc2[r]);
      float ps = 0.f;
#pragma unroll
      for (int r = 0; r < 16; ++r) ps += sc[r];
      ssum += ps;

      // pack unnormalized P to A-frags (in-register, key perm matched by Vt)
      bf16x8 pf[2];
#pragma unroll
      for (int t2 = 0; t2 < 2; ++t2)
        pf[t2] = mk8(pk2bf(sc[8 * t2 + 0], sc[8 * t2 + 1]), pk2bf(sc[8 * t2 + 2], sc[8 * t2 + 3]),
                     pk2bf(sc[8 * t2 + 4], sc[8 * t2 + 5]), pk2bf(sc[8 * t2 + 6], sc[8 * t2 + 7]));

      if (c == 3) {
        ssum += __shfl_xor(ssum, 32);
        if (lane < 32) sRed[(qp * 32 + l31) * 2 + h] = ssum;
        ssum = 0.f;
        __syncthreads();
        if (h == 0 && lane < 32) {
          f32x2 s2 = *(const f32x2*)&sRed[(qp * 32 + l31) * 2];
          sLinv[qp * 32 + l31] = __fdividef(1.0f, s2[0] + s2[1]);
        }
      }

      // ---- PV: own 32 keys x all 128 d (h-partial oj) ----
      const short* pV = &ring[slot][8192];
#pragma unroll
      for (int t2 = 0; t2 < 2; ++t2) {
#pragma unroll
        for (int dt = 0; dt < 4; ++dt) {
          bf16x8 bv = *(const bf16x8*)(pV + aV2[t2] + dt * 2048);
          oj[dt] = __builtin_amdgcn_mfma_f32_32x32x16_bf16(pf[t2], bv, oj[dt], 0, 0, 0);
        }
      }
    }
  }

  // ---- epilogue: final normalize, cross-h reduce via LDS, store ----
  __syncthreads();
  f32x4 lv[4];
#pragma unroll
  for (int g = 0; g < 4; ++g) lv[g] = *(const f32x4*)&sLinv[qp * 32 + g * 8 + hi * 4];
  float of[4][16];
#pragma unroll
  for (int d = 0; d < 4; ++d)
#pragma unroll
    for (int r = 0; r < 16; ++r) of[d][r] = oa[d][r] + oj[d][r] * lv[r >> 2][r & 3];

  float* ex = (float*)&ring[0][0];  // [qp][32 q][128 d] = 32 KB
  if (h == 1) {
#pragma unroll
    for (int d = 0; d < 4; ++d)
#pragma unroll
      for (int r = 0; r < 16; ++r) {
        int q = (r & 3) + 8 * (r >> 2) + 4 * hi;
        ex[qp * 4096 + q * 128 + d * 32 + l31] = of[d][r];
      }
  }
  __syncthreads();
  if (h == 0) {
    float* Og = O + ((size_t)bh * S_LEN + q0 + qp * 32) * D_DIM;
#pragma unroll
    for (int d = 0; d < 4; ++d)
#pragma unroll
      for (int r = 0; r < 16; ++r) {
        int q = (r & 3) + 8 * (r >> 2) + 4 * hi;
        float val = of[d][r] + ex[qp * 4096 + q * 128 + d * 32 + l31];
        Og[(size_t)q * D_DIM + d * 32 + l31] = val;
      }
  }
}

extern "C" void kernel_launch(void* const* d_in, const int* in_sizes, int n_in,
                              void* d_out, int out_size, void* d_ws, size_t ws_size,
                              hipStream_t stream) {
  const float* Q = (const float*)d_in[0];
  const float* K = (const float*)d_in[1];
  const float* V = (const float*)d_in[2];
  float* Out = (float*)d_out;
  const size_t tElems = (size_t)32 * S_LEN * D_DIM;

  short* Kb  = (short*)d_ws;
  short* Vtb = Kb + tElems;

  pre_kernel<<<1024, 256, 0, stream>>>(K, V, Kb, Vtb);
  attn_main<<<1024, 256, 0, stream>>>(Kb, Vtb, Q, Out);
}